// Round 1
// baseline (320.474 us; speedup 1.0000x reference)
//
#include <hip/hip_runtime.h>
#include <math.h>

// ---------------------------------------------------------------------------
// QCNN forward, restructured:
//   layer0 gates (20x two-qubit, 2 LDS passes) -> per-row-vector layer1 gates
//   + pooled outer products (avoids the 1024^3 complex GEMM) -> tiny tail.
// Bit convention: qubit q <-> address bit (19-q)  (qubit 0 = MSB).
// Gate digit r = 2*bit(pa) + bit(pb) where pa = bit position of qubit 'a'.
// ---------------------------------------------------------------------------

__device__ __forceinline__ float2 cmul(float2 a, float2 b) {
  return make_float2(a.x * b.x - a.y * b.y, a.x * b.y + a.y * b.x);
}
__device__ __forceinline__ float2 cmadd(float2 acc, float2 a, float2 b) {
  acc.x = fmaf(a.x, b.x, fmaf(-a.y, b.y, acc.x));
  acc.y = fmaf(a.x, b.y, fmaf(a.y, b.x, acc.y));
  return acc;
}
// acc += a * conj(b)
__device__ __forceinline__ float2 cmaddc(float2 acc, float2 a, float2 b) {
  acc.x = fmaf(a.x, b.x, fmaf(a.y, b.y, acc.x));
  acc.y = fmaf(a.y, b.x, fmaf(-a.x, b.y, acc.y));
  return acc;
}
// LDS pad: +1 float2 every 16 to break power-of-2 bank strides
__device__ __forceinline__ int pad(int e) { return e + (e >> 4); }

// spread bits: bit j -> bit 2j (Morton), valid for v < 2^16
__device__ __forceinline__ unsigned spread(unsigned v) {
  v = (v | (v << 8)) & 0x00FF00FFu;
  v = (v | (v << 4)) & 0x0F0F0F0Fu;
  v = (v | (v << 2)) & 0x33333333u;
  v = (v | (v << 1)) & 0x55555555u;
  return v;
}

__device__ __forceinline__ void gate4(float2& v0, float2& v1, float2& v2, float2& v3,
                                      const float2 (&U)[16]) {
  float2 n0 = cmul(U[0], v0);  n0 = cmadd(n0, U[1], v1);  n0 = cmadd(n0, U[2], v2);  n0 = cmadd(n0, U[3], v3);
  float2 n1 = cmul(U[4], v0);  n1 = cmadd(n1, U[5], v1);  n1 = cmadd(n1, U[6], v2);  n1 = cmadd(n1, U[7], v3);
  float2 n2 = cmul(U[8], v0);  n2 = cmadd(n2, U[9], v1);  n2 = cmadd(n2, U[10], v2); n2 = cmadd(n2, U[11], v3);
  float2 n3 = cmul(U[12], v0); n3 = cmadd(n3, U[13], v1); n3 = cmadd(n3, U[14], v2); n3 = cmadd(n3, U[15], v3);
  v0 = n0; v1 = n1; v2 = n2; v3 = n3;
}

// apply a 2-qubit gate at bit positions (pa, pb) over a 2^13-element LDS tile
__device__ __forceinline__ void apply_gate_tile13(float2* t, const float2 (&U)[16],
                                                  int pa, int pb, int tid) {
  int p0 = pa < pb ? pa : pb;
  int p1 = pa < pb ? pb : pa;
  int m0 = (1 << p0) - 1, m1 = (1 << p1) - 1;
  int ia = 1 << pa, ib = 1 << pb;
#pragma unroll
  for (int g = tid; g < 2048; g += 256) {
    int idx = ((g & ~m0) << 1) | (g & m0);
    idx = ((idx & ~m1) << 1) | (idx & m1);
    int e0 = pad(idx), e1 = pad(idx | ib), e2 = pad(idx | ia), e3 = pad(idx | ia | ib);
    float2 v0 = t[e0], v1 = t[e1], v2 = t[e2], v3 = t[e3];
    gate4(v0, v1, v2, v3, U);
    t[e0] = v0; t[e1] = v1; t[e2] = v2; t[e3] = v3;
  }
}

// ---------------------------------------------------------------------------
// Kernel A: U[l] = expm(A - A^H), fp64 scaling & squaring Taylor. 5 threads.
// ---------------------------------------------------------------------------
__global__ void expm_kernel(const float* __restrict__ Hre, const float* __restrict__ Him,
                            float2* __restrict__ Uout) {
  int l = threadIdx.x;
  if (l >= 5) return;
  double Tr[16], Ti[16], Er[16], Ei[16], Pr[16], Pi[16], Qr[16], Qi[16];
#pragma unroll
  for (int r = 0; r < 4; r++)
#pragma unroll
    for (int c = 0; c < 4; c++) {
      Tr[r * 4 + c] = (double)Hre[l * 16 + r * 4 + c] - (double)Hre[l * 16 + c * 4 + r];
      Ti[r * 4 + c] = (double)Him[l * 16 + r * 4 + c] + (double)Him[l * 16 + c * 4 + r];
    }
  double nrm = 0.0;
  for (int r = 0; r < 4; r++) {
    double rs = 0.0;
    for (int c = 0; c < 4; c++) rs += sqrt(Tr[r * 4 + c] * Tr[r * 4 + c] + Ti[r * 4 + c] * Ti[r * 4 + c]);
    nrm = fmax(nrm, rs);
  }
  int s = 0;
  while (nrm > 0.25 && s < 60) { nrm *= 0.5; s++; }
  double sc = ldexp(1.0, -s);
  for (int k = 0; k < 16; k++) { Tr[k] *= sc; Ti[k] *= sc; }
  for (int k = 0; k < 16; k++) {
    double id = ((k & 3) == (k >> 2)) ? 1.0 : 0.0;
    Er[k] = id; Ei[k] = 0.0; Pr[k] = id; Pi[k] = 0.0;
  }
  for (int k = 1; k <= 20; k++) {
    for (int r = 0; r < 4; r++)
      for (int c = 0; c < 4; c++) {
        double qr = 0.0, qi = 0.0;
        for (int m = 0; m < 4; m++) {
          qr += Pr[r * 4 + m] * Tr[m * 4 + c] - Pi[r * 4 + m] * Ti[m * 4 + c];
          qi += Pr[r * 4 + m] * Ti[m * 4 + c] + Pi[r * 4 + m] * Tr[m * 4 + c];
        }
        Qr[r * 4 + c] = qr; Qi[r * 4 + c] = qi;
      }
    double inv = 1.0 / (double)k;
    for (int j = 0; j < 16; j++) {
      Pr[j] = Qr[j] * inv; Pi[j] = Qi[j] * inv;
      Er[j] += Pr[j]; Ei[j] += Pi[j];
    }
  }
  for (int it = 0; it < s; it++) {
    for (int r = 0; r < 4; r++)
      for (int c = 0; c < 4; c++) {
        double qr = 0.0, qi = 0.0;
        for (int m = 0; m < 4; m++) {
          qr += Er[r * 4 + m] * Er[m * 4 + c] - Ei[r * 4 + m] * Ei[m * 4 + c];
          qi += Er[r * 4 + m] * Ei[m * 4 + c] + Ei[r * 4 + m] * Er[m * 4 + c];
        }
        Qr[r * 4 + c] = qr; Qi[r * 4 + c] = qi;
      }
    for (int j = 0; j < 16; j++) { Er[j] = Qr[j]; Ei[j] = Qi[j]; }
  }
  for (int j = 0; j < 16; j++) Uout[l * 16 + j] = make_float2((float)Er[j], (float)Ei[j]);
}

// ---------------------------------------------------------------------------
// Kernel B: layer-0 pass 1. Contiguous tile = addr bits 0..12 (8192 cplx).
// Gates fully inside: evens (qubits 18/19..8/9) then odds (17/18..9/10).
// Reads deinterleaved psi, writes interleaved state.
// ---------------------------------------------------------------------------
__global__ __launch_bounds__(256) void l0_pass1(const float* __restrict__ pre,
                                                const float* __restrict__ pim,
                                                const float2* __restrict__ Umat,
                                                float2* __restrict__ state) {
  extern __shared__ float2 tile[];
  int tid = threadIdx.x;
  int bid = blockIdx.x;
  int b = bid >> 7, hi = bid & 127;
  size_t base = ((size_t)b << 20) | ((size_t)hi << 13);
  float2 U[16];
#pragma unroll
  for (int k = 0; k < 16; k++) U[k] = Umat[k];
  for (int e = tid; e < 8192; e += 256)
    tile[pad(e)] = make_float2(pre[base + e], pim[base + e]);
  __syncthreads();
  // (pa,pb): evens {1,0}..{11,10}; odds {2,1}..{10,9}
  const int gp[11][2] = {{1,0},{3,2},{5,4},{7,6},{9,8},{11,10},
                         {2,1},{4,3},{6,5},{8,7},{10,9}};
#pragma unroll
  for (int gi = 0; gi < 11; gi++) {
    apply_gate_tile13(tile, U, gp[gi][0], gp[gi][1], tid);
    __syncthreads();
  }
  for (int e = tid; e < 8192; e += 256) state[base + e] = tile[pad(e)];
}

// ---------------------------------------------------------------------------
// Kernel C: layer-0 pass 2. Tile = addr bits {0..3} U {11..19} (local L0..L3 ->
// bits 0..3, L4..L12 -> bits 11..19). Evens (q6/7..0/1) then odds incl. wrap.
// In-place on state.
// ---------------------------------------------------------------------------
__global__ __launch_bounds__(256) void l0_pass2(const float2* __restrict__ Umat,
                                                float2* __restrict__ state) {
  extern __shared__ float2 tile[];
  int tid = threadIdx.x;
  int bid = blockIdx.x;
  int b = bid >> 7, mid = bid & 127;
  size_t base = ((size_t)b << 20) | ((size_t)mid << 4);
  float2 U[16];
#pragma unroll
  for (int k = 0; k < 16; k++) U[k] = Umat[k];
  for (int e = tid; e < 8192; e += 256) {
    size_t a = base + (((size_t)(e >> 4)) << 11) + (size_t)(e & 15);
    tile[pad(e)] = state[a];
  }
  __syncthreads();
  // local positions: evens {6,5},{8,7},{10,9},{12,11}; odds {5,4},{7,6},{9,8},{11,10}; wrap {0,12}
  const int gp[9][2] = {{6,5},{8,7},{10,9},{12,11},
                        {5,4},{7,6},{9,8},{11,10},{0,12}};
#pragma unroll
  for (int gi = 0; gi < 9; gi++) {
    apply_gate_tile13(tile, U, gp[gi][0], gp[gi][1], tid);
    __syncthreads();
  }
  for (int e = tid; e < 8192; e += 256) {
    size_t a = base + (((size_t)(e >> 4)) << 11) + (size_t)(e & 15);
    state[a] = tile[pad(e)];
  }
}

// ---------------------------------------------------------------------------
// Kernel D: pool0 + layer1 gates + pool1 (partials).
// Block = (b, t_hi); gathers 8 t-vectors (1024 cplx each, Morton-interleaved),
// applies 10 layer-1 gates, accumulates 32x32 partial rho2 via outer products.
// ---------------------------------------------------------------------------
__global__ __launch_bounds__(256) void pool_l1(const float2* __restrict__ Umat,
                                               const float2* __restrict__ state,
                                               float2* __restrict__ partial) {
  extern __shared__ float2 w[];
  int tid = threadIdx.x;
  int bid = blockIdx.x;
  int b = bid >> 7, thi = bid & 127;
  size_t bbase = (size_t)b << 20;
  float2 U[16];
#pragma unroll
  for (int k = 0; k < 16; k++) U[k] = Umat[16 + k];
  unsigned tbase = spread((unsigned)(thi << 3)) << 1;  // t-high bits -> addr bits 7,9,..,19
  for (int e = tid; e < 8192; e += 256) {
    int i_lo = e & 7, t_lo = (e >> 3) & 7, i_hi = e >> 6;
    int i = (i_hi << 3) | i_lo;
    unsigned addr = tbase | (spread((unsigned)t_lo) << 1) | spread((unsigned)i);
    w[pad((t_lo << 10) | i)] = state[bbase + (size_t)addr];
  }
  __syncthreads();
  // layer-1 gates on i (new qubit k <-> i bit 9-k): evens then odds (wrap = {0,9})
  const int gp[10][2] = {{9,8},{7,6},{5,4},{3,2},{1,0},
                         {8,7},{6,5},{4,3},{2,1},{0,9}};
#pragma unroll
  for (int gi = 0; gi < 10; gi++) {
    apply_gate_tile13(w, U, gp[gi][0], gp[gi][1], tid);
    __syncthreads();
  }
  // pool1: rho2[u,v] = sum_{t_lo,s} w[su|iu] * conj(w[su|iv]); 2x2 blocked
  int ub = tid >> 4, vb = tid & 15;
  int u0 = ub << 1, v0 = vb << 1;
  int iu0 = (int)spread((unsigned)u0), iu1 = iu0 | 1;
  int iv0 = (int)spread((unsigned)v0), iv1 = iv0 | 1;
  float2 a00 = {0.f, 0.f}, a01 = {0.f, 0.f}, a10 = {0.f, 0.f}, a11 = {0.f, 0.f};
  for (int t_lo = 0; t_lo < 8; t_lo++) {
    int off = t_lo << 10;
#pragma unroll
    for (int s = 0; s < 32; s++) {
      int su = off + (int)(spread((unsigned)s) << 1);
      float2 x0 = w[pad(su + iu0)], x1 = w[pad(su + iu1)];
      float2 y0 = w[pad(su + iv0)], y1 = w[pad(su + iv1)];
      a00 = cmaddc(a00, x0, y0); a01 = cmaddc(a01, x0, y1);
      a10 = cmaddc(a10, x1, y0); a11 = cmaddc(a11, x1, y1);
    }
  }
  float2* outp = partial + ((size_t)bid << 10);
  outp[(u0 << 5) + v0] = a00;
  outp[(u0 << 5) + v0 + 1] = a01;
  outp[((u0 + 1) << 5) + v0] = a10;
  outp[((u0 + 1) << 5) + v0 + 1] = a11;
}

// ---------------------------------------------------------------------------
// Kernel E: reduce 128 partials per batch -> rho32 (as floats)
// ---------------------------------------------------------------------------
__global__ __launch_bounds__(256) void reduce_partials(const float* __restrict__ partial,
                                                       float* __restrict__ rho32) {
  int idx = blockIdx.x * 256 + threadIdx.x;  // 0..8191 (4 batches * 2048 floats)
  int b = idx >> 11, p = idx & 2047;
  float acc = 0.f;
#pragma unroll 4
  for (int h = 0; h < 128; h++) acc += partial[(((size_t)(b * 128 + h)) << 11) + (size_t)p];
  rho32[idx] = acc;
}

// ---------------------------------------------------------------------------
// Kernel F: layers 2..4 (32x32 -> 2x2 dm) + measure. One block per batch.
// ---------------------------------------------------------------------------
__global__ __launch_bounds__(256) void finish(const float2* __restrict__ Umat,
                                              const float2* __restrict__ rho32,
                                              float* __restrict__ out) {
  __shared__ float2 rho[1024];
  __shared__ float2 r3[64];
  __shared__ float2 r4[16];
  int tid = threadIdx.x;
  int b = blockIdx.x;
  for (int p = tid; p < 1024; p += 256) rho[p] = rho32[(b << 10) + p];
  __syncthreads();

  float2 U[16], Uc[16];
#pragma unroll
  for (int k = 0; k < 16; k++) { U[k] = Umat[32 + k]; Uc[k] = make_float2(U[k].x, -U[k].y); }
  // layer 2 (nq=5): pairs (0,1),(2,3),(1,2),(3,4) -> bit positions below
  const int gl2[4][2] = {{4,3},{2,1},{3,2},{1,0}};
#pragma unroll
  for (int gi = 0; gi < 4; gi++) {
    int pa = gl2[gi][0], pb = gl2[gi][1];
    int p0 = pa < pb ? pa : pb, p1 = pa < pb ? pb : pa;
    int m0 = (1 << p0) - 1, m1 = (1 << p1) - 1;
    int ia = 1 << pa, ib = 1 << pb;
    {  // ket: 32 cols x 8 groups
      int j = tid >> 3, g = tid & 7;
      int idx = ((g & ~m0) << 1) | (g & m0);
      idx = ((idx & ~m1) << 1) | (idx & m1);
      float2 v0 = rho[idx * 32 + j], v1 = rho[(idx | ib) * 32 + j];
      float2 v2 = rho[(idx | ia) * 32 + j], v3 = rho[(idx | ia | ib) * 32 + j];
      gate4(v0, v1, v2, v3, U);
      rho[idx * 32 + j] = v0; rho[(idx | ib) * 32 + j] = v1;
      rho[(idx | ia) * 32 + j] = v2; rho[(idx | ia | ib) * 32 + j] = v3;
    }
    __syncthreads();
    {  // bra with conj(U)
      int i = tid >> 3, g = tid & 7;
      int idx = ((g & ~m0) << 1) | (g & m0);
      idx = ((idx & ~m1) << 1) | (idx & m1);
      float2 v0 = rho[i * 32 + idx], v1 = rho[i * 32 + (idx | ib)];
      float2 v2 = rho[i * 32 + (idx | ia)], v3 = rho[i * 32 + (idx | ia | ib)];
      gate4(v0, v1, v2, v3, Uc);
      rho[i * 32 + idx] = v0; rho[i * 32 + (idx | ib)] = v1;
      rho[i * 32 + (idx | ia)] = v2; rho[i * 32 + (idx | ia | ib)] = v3;
    }
    __syncthreads();
  }
  // pool2: traced bits {4,2}; kept u2->bit3, u1->bit1, u0->bit0
  if (tid < 64) {
    int u = tid >> 3, v = tid & 7;
    float2 acc = {0.f, 0.f};
#pragma unroll
    for (int s = 0; s < 4; s++) {
      int iu = ((s >> 1) << 4) | ((u >> 2) << 3) | ((s & 1) << 2) | (((u >> 1) & 1) << 1) | (u & 1);
      int iv = ((s >> 1) << 4) | ((v >> 2) << 3) | ((s & 1) << 2) | (((v >> 1) & 1) << 1) | (v & 1);
      float2 x = rho[iu * 32 + iv];
      acc.x += x.x; acc.y += x.y;
    }
    r3[u * 8 + v] = acc;
  }
  __syncthreads();

#pragma unroll
  for (int k = 0; k < 16; k++) { U[k] = Umat[48 + k]; Uc[k] = make_float2(U[k].x, -U[k].y); }
  // layer 3 (nq=3): pairs (0,1)->(2,1), (1,2)->(1,0)
  const int gl3[2][2] = {{2,1},{1,0}};
#pragma unroll
  for (int gi = 0; gi < 2; gi++) {
    int pa = gl3[gi][0], pb = gl3[gi][1];
    int p0 = pa < pb ? pa : pb, p1 = pa < pb ? pb : pa;
    int m0 = (1 << p0) - 1, m1 = (1 << p1) - 1;
    int ia = 1 << pa, ib = 1 << pb;
    if (tid < 16) {
      int j = tid >> 1, g = tid & 1;
      int idx = ((g & ~m0) << 1) | (g & m0);
      idx = ((idx & ~m1) << 1) | (idx & m1);
      float2 v0 = r3[idx * 8 + j], v1 = r3[(idx | ib) * 8 + j];
      float2 v2 = r3[(idx | ia) * 8 + j], v3 = r3[(idx | ia | ib) * 8 + j];
      gate4(v0, v1, v2, v3, U);
      r3[idx * 8 + j] = v0; r3[(idx | ib) * 8 + j] = v1;
      r3[(idx | ia) * 8 + j] = v2; r3[(idx | ia | ib) * 8 + j] = v3;
    }
    __syncthreads();
    if (tid < 16) {
      int i = tid >> 1, g = tid & 1;
      int idx = ((g & ~m0) << 1) | (g & m0);
      idx = ((idx & ~m1) << 1) | (idx & m1);
      float2 v0 = r3[i * 8 + idx], v1 = r3[i * 8 + (idx | ib)];
      float2 v2 = r3[i * 8 + (idx | ia)], v3 = r3[i * 8 + (idx | ia | ib)];
      gate4(v0, v1, v2, v3, Uc);
      r3[i * 8 + idx] = v0; r3[i * 8 + (idx | ib)] = v1;
      r3[i * 8 + (idx | ia)] = v2; r3[i * 8 + (idx | ia | ib)] = v3;
    }
    __syncthreads();
  }
  // pool3: traced bit 2
  if (tid < 16) {
    int u = tid >> 2, v = tid & 3;
    float2 acc = {0.f, 0.f};
#pragma unroll
    for (int s = 0; s < 2; s++) {
      float2 x = r3[((s << 2) | u) * 8 + ((s << 2) | v)];
      acc.x += x.x; acc.y += x.y;
    }
    r4[u * 4 + v] = acc;
  }
  __syncthreads();

#pragma unroll
  for (int k = 0; k < 16; k++) { U[k] = Umat[64 + k]; Uc[k] = make_float2(U[k].x, -U[k].y); }
  // layer 4 (nq=2): single gate = full 4x4 on ket, conj on bra
  if (tid < 4) {
    int j = tid;
    float2 v0 = r4[0 * 4 + j], v1 = r4[1 * 4 + j], v2 = r4[2 * 4 + j], v3 = r4[3 * 4 + j];
    gate4(v0, v1, v2, v3, U);
    r4[0 * 4 + j] = v0; r4[1 * 4 + j] = v1; r4[2 * 4 + j] = v2; r4[3 * 4 + j] = v3;
  }
  __syncthreads();
  if (tid < 4) {
    int i = tid;
    float2 v0 = r4[i * 4 + 0], v1 = r4[i * 4 + 1], v2 = r4[i * 4 + 2], v3 = r4[i * 4 + 3];
    gate4(v0, v1, v2, v3, Uc);
    r4[i * 4 + 0] = v0; r4[i * 4 + 1] = v1; r4[i * 4 + 2] = v2; r4[i * 4 + 3] = v3;
  }
  __syncthreads();
  // pool4 + measure: rho5[0,0] = r4[0,0] + r4[2,2]; output its real part
  if (tid == 0) out[b] = r4[0].x + r4[10].x;
}

// ---------------------------------------------------------------------------
extern "C" void kernel_launch(void* const* d_in, const int* in_sizes, int n_in,
                              void* d_out, int out_size, void* d_ws, size_t ws_size,
                              hipStream_t stream) {
  const float* psi_re = (const float*)d_in[0];
  const float* psi_im = (const float*)d_in[1];
  const float* H_re = (const float*)d_in[2];
  const float* H_im = (const float*)d_in[3];
  float* out = (float*)d_out;

  char* ws = (char*)d_ws;
  float2* Umat = (float2*)ws;                                   // 5*16 float2
  float2* state = (float2*)(ws + 4096);                         // 4M float2 = 32 MB
  float* partial = (float*)(ws + 4096 + ((size_t)1 << 25));     // 512*2048 floats = 4 MB
  float* rho32 = (float*)(ws + 4096 + ((size_t)1 << 25) + ((size_t)1 << 22));  // 8192 floats

  const size_t LDS_BYTES = 8704 * sizeof(float2);  // 8192 + pad

  hipLaunchKernelGGL(expm_kernel, dim3(1), dim3(64), 0, stream, H_re, H_im, Umat);
  hipLaunchKernelGGL(l0_pass1, dim3(512), dim3(256), LDS_BYTES, stream,
                     psi_re, psi_im, Umat, state);
  hipLaunchKernelGGL(l0_pass2, dim3(512), dim3(256), LDS_BYTES, stream, Umat, state);
  hipLaunchKernelGGL(pool_l1, dim3(512), dim3(256), LDS_BYTES, stream,
                     Umat, state, (float2*)partial);
  hipLaunchKernelGGL(reduce_partials, dim3(32), dim3(256), 0, stream, partial, rho32);
  hipLaunchKernelGGL(finish, dim3(4), dim3(256), 0, stream, Umat, (const float2*)rho32, out);
}

// Round 2
// 239.186 us; speedup vs baseline: 1.3398x; 1.3398x over previous
//
#include <hip/hip_runtime.h>
#include <math.h>

// ---------------------------------------------------------------------------
// QCNN forward, restructured:
//   layer0 gates (20x two-qubit, 2 LDS passes) -> per-row-vector layer1 gates
//   + pooled outer products (avoids the 1024^3 complex GEMM) -> tiny tail.
// Bit convention: qubit q <-> address bit (19-q)  (qubit 0 = MSB).
// Gate digit r = 2*bit(pa) + bit(pb) where pa = bit position of qubit 'a'.
// ---------------------------------------------------------------------------

__device__ __forceinline__ float2 cmul(float2 a, float2 b) {
  return make_float2(a.x * b.x - a.y * b.y, a.x * b.y + a.y * b.x);
}
__device__ __forceinline__ float2 cmadd(float2 acc, float2 a, float2 b) {
  acc.x = fmaf(a.x, b.x, fmaf(-a.y, b.y, acc.x));
  acc.y = fmaf(a.x, b.y, fmaf(a.y, b.x, acc.y));
  return acc;
}
// acc += a * conj(b)
__device__ __forceinline__ float2 cmaddc(float2 acc, float2 a, float2 b) {
  acc.x = fmaf(a.x, b.x, fmaf(a.y, b.y, acc.x));
  acc.y = fmaf(a.y, b.x, fmaf(-a.x, b.y, acc.y));
  return acc;
}
// LDS pad: +1 float2 every 16 to break power-of-2 bank strides
__device__ __forceinline__ int pad(int e) { return e + (e >> 4); }

// spread bits: bit j -> bit 2j (Morton), valid for v < 2^16
__device__ __forceinline__ unsigned spread(unsigned v) {
  v = (v | (v << 8)) & 0x00FF00FFu;
  v = (v | (v << 4)) & 0x0F0F0F0Fu;
  v = (v | (v << 2)) & 0x33333333u;
  v = (v | (v << 1)) & 0x55555555u;
  return v;
}

__device__ __forceinline__ void gate4(float2& v0, float2& v1, float2& v2, float2& v3,
                                      const float2 (&U)[16]) {
  float2 n0 = cmul(U[0], v0);  n0 = cmadd(n0, U[1], v1);  n0 = cmadd(n0, U[2], v2);  n0 = cmadd(n0, U[3], v3);
  float2 n1 = cmul(U[4], v0);  n1 = cmadd(n1, U[5], v1);  n1 = cmadd(n1, U[6], v2);  n1 = cmadd(n1, U[7], v3);
  float2 n2 = cmul(U[8], v0);  n2 = cmadd(n2, U[9], v1);  n2 = cmadd(n2, U[10], v2); n2 = cmadd(n2, U[11], v3);
  float2 n3 = cmul(U[12], v0); n3 = cmadd(n3, U[13], v1); n3 = cmadd(n3, U[14], v2); n3 = cmadd(n3, U[15], v3);
  v0 = n0; v1 = n1; v2 = n2; v3 = n3;
}

// apply a 2-qubit gate at bit positions (pa, pb) over a 2^13-element LDS tile
__device__ __forceinline__ void apply_gate_tile13(float2* t, const float2 (&U)[16],
                                                  int pa, int pb, int tid) {
  int p0 = pa < pb ? pa : pb;
  int p1 = pa < pb ? pb : pa;
  int m0 = (1 << p0) - 1, m1 = (1 << p1) - 1;
  int ia = 1 << pa, ib = 1 << pb;
#pragma unroll
  for (int g = tid; g < 2048; g += 256) {
    int idx = ((g & ~m0) << 1) | (g & m0);
    idx = ((idx & ~m1) << 1) | (idx & m1);
    int e0 = pad(idx), e1 = pad(idx | ib), e2 = pad(idx | ia), e3 = pad(idx | ia | ib);
    float2 v0 = t[e0], v1 = t[e1], v2 = t[e2], v3 = t[e3];
    gate4(v0, v1, v2, v3, U);
    t[e0] = v0; t[e1] = v1; t[e2] = v2; t[e3] = v3;
  }
}

// ---------------------------------------------------------------------------
// Kernel A: U[l] = expm(A - A^H), fp64 scaling & squaring Taylor.
// Lane-parallel: 5 waves (one per layer), lanes 0..15 hold one matrix element
// each; matmuls via __shfl broadcast. ~16x less work/lane, short dep chains.
// ---------------------------------------------------------------------------
__global__ __launch_bounds__(320) void expm_kernel(const float* __restrict__ Hre,
                                                   const float* __restrict__ Him,
                                                   float2* __restrict__ Uout) {
  int wave = threadIdx.x >> 6;
  int lane = threadIdx.x & 63;
  if (wave >= 5 || lane >= 16) return;
  int l = wave;
  int r = lane >> 2, c = lane & 3;
  // G = A - A^H (element (r,c))
  double tr = (double)Hre[l * 16 + r * 4 + c] - (double)Hre[l * 16 + c * 4 + r];
  double ti = (double)Him[l * 16 + r * 4 + c] + (double)Him[l * 16 + c * 4 + r];
  // norm: max over rows of sum_c |G[r,c]|
  double a = sqrt(tr * tr + ti * ti);
  a += __shfl_xor(a, 1, 64);
  a += __shfl_xor(a, 2, 64);
  double nrm = fmax(a, __shfl_xor(a, 4, 64));
  nrm = fmax(nrm, __shfl_xor(nrm, 8, 64));
  int s = 0;
  while (nrm > 0.25 && s < 60) { nrm *= 0.5; s++; }
  double sc = ldexp(1.0, -s);
  tr *= sc; ti *= sc;
  // Taylor: E = I + sum_{k=1..16} T^k / k!
  double id = (r == c) ? 1.0 : 0.0;
  double er = id, ei = 0.0, pr = id, pi = 0.0;
  for (int k = 1; k <= 16; k++) {
    double qr = 0.0, qi = 0.0;
#pragma unroll
    for (int m = 0; m < 4; m++) {
      double pmr = __shfl(pr, r * 4 + m, 64);
      double pmi = __shfl(pi, r * 4 + m, 64);
      double tmr = __shfl(tr, m * 4 + c, 64);
      double tmi = __shfl(ti, m * 4 + c, 64);
      qr = fma(pmr, tmr, fma(-pmi, tmi, qr));
      qi = fma(pmr, tmi, fma(pmi, tmr, qi));
    }
    double inv = 1.0 / (double)k;
    pr = qr * inv; pi = qi * inv;
    er += pr; ei += pi;
  }
  // squarings: E <- E^2, s times
  for (int it = 0; it < s; it++) {
    double qr = 0.0, qi = 0.0;
#pragma unroll
    for (int m = 0; m < 4; m++) {
      double amr = __shfl(er, r * 4 + m, 64);
      double ami = __shfl(ei, r * 4 + m, 64);
      double bmr = __shfl(er, m * 4 + c, 64);
      double bmi = __shfl(ei, m * 4 + c, 64);
      qr = fma(amr, bmr, fma(-ami, bmi, qr));
      qi = fma(amr, bmi, fma(ami, bmr, qi));
    }
    er = qr; ei = qi;
  }
  Uout[l * 16 + lane] = make_float2((float)er, (float)ei);
}

// ---------------------------------------------------------------------------
// Kernel B: layer-0 pass 1. Contiguous tile = addr bits 0..12 (8192 cplx).
// Gates fully inside: evens (qubits 18/19..8/9) then odds (17/18..9/10).
// Reads deinterleaved psi, writes interleaved state.
// ---------------------------------------------------------------------------
__global__ __launch_bounds__(256) void l0_pass1(const float* __restrict__ pre,
                                                const float* __restrict__ pim,
                                                const float2* __restrict__ Umat,
                                                float2* __restrict__ state) {
  extern __shared__ float2 tile[];
  int tid = threadIdx.x;
  int bid = blockIdx.x;
  int b = bid >> 7, hi = bid & 127;
  size_t base = ((size_t)b << 20) | ((size_t)hi << 13);
  float2 U[16];
#pragma unroll
  for (int k = 0; k < 16; k++) U[k] = Umat[k];
  for (int e = tid; e < 8192; e += 256)
    tile[pad(e)] = make_float2(pre[base + e], pim[base + e]);
  __syncthreads();
  // (pa,pb): evens {1,0}..{11,10}; odds {2,1}..{10,9}
  const int gp[11][2] = {{1,0},{3,2},{5,4},{7,6},{9,8},{11,10},
                         {2,1},{4,3},{6,5},{8,7},{10,9}};
#pragma unroll
  for (int gi = 0; gi < 11; gi++) {
    apply_gate_tile13(tile, U, gp[gi][0], gp[gi][1], tid);
    __syncthreads();
  }
  for (int e = tid; e < 8192; e += 256) state[base + e] = tile[pad(e)];
}

// ---------------------------------------------------------------------------
// Kernel C: layer-0 pass 2. Tile = addr bits {0..3} U {11..19} (local L0..L3 ->
// bits 0..3, L4..L12 -> bits 11..19). Evens (q6/7..0/1) then odds incl. wrap.
// In-place on state.
// ---------------------------------------------------------------------------
__global__ __launch_bounds__(256) void l0_pass2(const float2* __restrict__ Umat,
                                                float2* __restrict__ state) {
  extern __shared__ float2 tile[];
  int tid = threadIdx.x;
  int bid = blockIdx.x;
  int b = bid >> 7, mid = bid & 127;
  size_t base = ((size_t)b << 20) | ((size_t)mid << 4);
  float2 U[16];
#pragma unroll
  for (int k = 0; k < 16; k++) U[k] = Umat[k];
  for (int e = tid; e < 8192; e += 256) {
    size_t a = base + (((size_t)(e >> 4)) << 11) + (size_t)(e & 15);
    tile[pad(e)] = state[a];
  }
  __syncthreads();
  // local positions: evens {6,5},{8,7},{10,9},{12,11}; odds {5,4},{7,6},{9,8},{11,10}; wrap {0,12}
  const int gp[9][2] = {{6,5},{8,7},{10,9},{12,11},
                        {5,4},{7,6},{9,8},{11,10},{0,12}};
#pragma unroll
  for (int gi = 0; gi < 9; gi++) {
    apply_gate_tile13(tile, U, gp[gi][0], gp[gi][1], tid);
    __syncthreads();
  }
  for (int e = tid; e < 8192; e += 256) {
    size_t a = base + (((size_t)(e >> 4)) << 11) + (size_t)(e & 15);
    state[a] = tile[pad(e)];
  }
}

// ---------------------------------------------------------------------------
// Kernel D: pool0 + layer1 gates + pool1 (partials).
// Block = (b, t_hi); gathers 8 t-vectors (1024 cplx each, Morton-interleaved),
// applies 10 layer-1 gates, accumulates 32x32 partial rho2 via outer products.
// ---------------------------------------------------------------------------
__global__ __launch_bounds__(256) void pool_l1(const float2* __restrict__ Umat,
                                               const float2* __restrict__ state,
                                               float2* __restrict__ partial) {
  extern __shared__ float2 w[];
  int tid = threadIdx.x;
  int bid = blockIdx.x;
  int b = bid >> 7, thi = bid & 127;
  size_t bbase = (size_t)b << 20;
  float2 U[16];
#pragma unroll
  for (int k = 0; k < 16; k++) U[k] = Umat[16 + k];
  unsigned tbase = spread((unsigned)(thi << 3)) << 1;  // t-high bits -> addr bits 7,9,..,19
  for (int e = tid; e < 8192; e += 256) {
    int i_lo = e & 7, t_lo = (e >> 3) & 7, i_hi = e >> 6;
    int i = (i_hi << 3) | i_lo;
    unsigned addr = tbase | (spread((unsigned)t_lo) << 1) | spread((unsigned)i);
    w[pad((t_lo << 10) | i)] = state[bbase + (size_t)addr];
  }
  __syncthreads();
  // layer-1 gates on i (new qubit k <-> i bit 9-k): evens then odds (wrap = {0,9})
  const int gp[10][2] = {{9,8},{7,6},{5,4},{3,2},{1,0},
                         {8,7},{6,5},{4,3},{2,1},{0,9}};
#pragma unroll
  for (int gi = 0; gi < 10; gi++) {
    apply_gate_tile13(w, U, gp[gi][0], gp[gi][1], tid);
    __syncthreads();
  }
  // pool1: rho2[u,v] = sum_{t_lo,s} w[su|iu] * conj(w[su|iv]); 2x2 blocked
  int ub = tid >> 4, vb = tid & 15;
  int u0 = ub << 1, v0 = vb << 1;
  int iu0 = (int)spread((unsigned)u0), iu1 = iu0 | 1;
  int iv0 = (int)spread((unsigned)v0), iv1 = iv0 | 1;
  float2 a00 = {0.f, 0.f}, a01 = {0.f, 0.f}, a10 = {0.f, 0.f}, a11 = {0.f, 0.f};
  for (int t_lo = 0; t_lo < 8; t_lo++) {
    int off = t_lo << 10;
#pragma unroll
    for (int s = 0; s < 32; s++) {
      int su = off + (int)(spread((unsigned)s) << 1);
      float2 x0 = w[pad(su + iu0)], x1 = w[pad(su + iu1)];
      float2 y0 = w[pad(su + iv0)], y1 = w[pad(su + iv1)];
      a00 = cmaddc(a00, x0, y0); a01 = cmaddc(a01, x0, y1);
      a10 = cmaddc(a10, x1, y0); a11 = cmaddc(a11, x1, y1);
    }
  }
  float2* outp = partial + ((size_t)bid << 10);
  outp[(u0 << 5) + v0] = a00;
  outp[(u0 << 5) + v0 + 1] = a01;
  outp[((u0 + 1) << 5) + v0] = a10;
  outp[((u0 + 1) << 5) + v0 + 1] = a11;
}

// ---------------------------------------------------------------------------
// Kernel E: reduce 128 partials per batch -> rho32 (as floats)
// ---------------------------------------------------------------------------
__global__ __launch_bounds__(256) void reduce_partials(const float* __restrict__ partial,
                                                       float* __restrict__ rho32) {
  int idx = blockIdx.x * 256 + threadIdx.x;  // 0..8191 (4 batches * 2048 floats)
  int b = idx >> 11, p = idx & 2047;
  float acc = 0.f;
#pragma unroll 4
  for (int h = 0; h < 128; h++) acc += partial[(((size_t)(b * 128 + h)) << 11) + (size_t)p];
  rho32[idx] = acc;
}

// ---------------------------------------------------------------------------
// Kernel F: layers 2..4 (32x32 -> 2x2 dm) + measure. One block per batch.
// ---------------------------------------------------------------------------
__global__ __launch_bounds__(256) void finish(const float2* __restrict__ Umat,
                                              const float2* __restrict__ rho32,
                                              float* __restrict__ out) {
  __shared__ float2 rho[1024];
  __shared__ float2 r3[64];
  __shared__ float2 r4[16];
  int tid = threadIdx.x;
  int b = blockIdx.x;
  for (int p = tid; p < 1024; p += 256) rho[p] = rho32[(b << 10) + p];
  __syncthreads();

  float2 U[16], Uc[16];
#pragma unroll
  for (int k = 0; k < 16; k++) { U[k] = Umat[32 + k]; Uc[k] = make_float2(U[k].x, -U[k].y); }
  // layer 2 (nq=5): pairs (0,1),(2,3),(1,2),(3,4) -> bit positions below
  const int gl2[4][2] = {{4,3},{2,1},{3,2},{1,0}};
#pragma unroll
  for (int gi = 0; gi < 4; gi++) {
    int pa = gl2[gi][0], pb = gl2[gi][1];
    int p0 = pa < pb ? pa : pb, p1 = pa < pb ? pb : pa;
    int m0 = (1 << p0) - 1, m1 = (1 << p1) - 1;
    int ia = 1 << pa, ib = 1 << pb;
    {  // ket: 32 cols x 8 groups
      int j = tid >> 3, g = tid & 7;
      int idx = ((g & ~m0) << 1) | (g & m0);
      idx = ((idx & ~m1) << 1) | (idx & m1);
      float2 v0 = rho[idx * 32 + j], v1 = rho[(idx | ib) * 32 + j];
      float2 v2 = rho[(idx | ia) * 32 + j], v3 = rho[(idx | ia | ib) * 32 + j];
      gate4(v0, v1, v2, v3, U);
      rho[idx * 32 + j] = v0; rho[(idx | ib) * 32 + j] = v1;
      rho[(idx | ia) * 32 + j] = v2; rho[(idx | ia | ib) * 32 + j] = v3;
    }
    __syncthreads();
    {  // bra with conj(U)
      int i = tid >> 3, g = tid & 7;
      int idx = ((g & ~m0) << 1) | (g & m0);
      idx = ((idx & ~m1) << 1) | (idx & m1);
      float2 v0 = rho[i * 32 + idx], v1 = rho[i * 32 + (idx | ib)];
      float2 v2 = rho[i * 32 + (idx | ia)], v3 = rho[i * 32 + (idx | ia | ib)];
      gate4(v0, v1, v2, v3, Uc);
      rho[i * 32 + idx] = v0; rho[i * 32 + (idx | ib)] = v1;
      rho[i * 32 + (idx | ia)] = v2; rho[i * 32 + (idx | ia | ib)] = v3;
    }
    __syncthreads();
  }
  // pool2: traced bits {4,2}; kept u2->bit3, u1->bit1, u0->bit0
  if (tid < 64) {
    int u = tid >> 3, v = tid & 7;
    float2 acc = {0.f, 0.f};
#pragma unroll
    for (int s = 0; s < 4; s++) {
      int iu = ((s >> 1) << 4) | ((u >> 2) << 3) | ((s & 1) << 2) | (((u >> 1) & 1) << 1) | (u & 1);
      int iv = ((s >> 1) << 4) | ((v >> 2) << 3) | ((s & 1) << 2) | (((v >> 1) & 1) << 1) | (v & 1);
      float2 x = rho[iu * 32 + iv];
      acc.x += x.x; acc.y += x.y;
    }
    r3[u * 8 + v] = acc;
  }
  __syncthreads();

#pragma unroll
  for (int k = 0; k < 16; k++) { U[k] = Umat[48 + k]; Uc[k] = make_float2(U[k].x, -U[k].y); }
  // layer 3 (nq=3): pairs (0,1)->(2,1), (1,2)->(1,0)
  const int gl3[2][2] = {{2,1},{1,0}};
#pragma unroll
  for (int gi = 0; gi < 2; gi++) {
    int pa = gl3[gi][0], pb = gl3[gi][1];
    int p0 = pa < pb ? pa : pb, p1 = pa < pb ? pb : pa;
    int m0 = (1 << p0) - 1, m1 = (1 << p1) - 1;
    int ia = 1 << pa, ib = 1 << pb;
    if (tid < 16) {
      int j = tid >> 1, g = tid & 1;
      int idx = ((g & ~m0) << 1) | (g & m0);
      idx = ((idx & ~m1) << 1) | (idx & m1);
      float2 v0 = r3[idx * 8 + j], v1 = r3[(idx | ib) * 8 + j];
      float2 v2 = r3[(idx | ia) * 8 + j], v3 = r3[(idx | ia | ib) * 8 + j];
      gate4(v0, v1, v2, v3, U);
      r3[idx * 8 + j] = v0; r3[(idx | ib) * 8 + j] = v1;
      r3[(idx | ia) * 8 + j] = v2; r3[(idx | ia | ib) * 8 + j] = v3;
    }
    __syncthreads();
    if (tid < 16) {
      int i = tid >> 1, g = tid & 1;
      int idx = ((g & ~m0) << 1) | (g & m0);
      idx = ((idx & ~m1) << 1) | (idx & m1);
      float2 v0 = r3[i * 8 + idx], v1 = r3[i * 8 + (idx | ib)];
      float2 v2 = r3[i * 8 + (idx | ia)], v3 = r3[i * 8 + (idx | ia | ib)];
      gate4(v0, v1, v2, v3, Uc);
      r3[i * 8 + idx] = v0; r3[i * 8 + (idx | ib)] = v1;
      r3[i * 8 + (idx | ia)] = v2; r3[i * 8 + (idx | ia | ib)] = v3;
    }
    __syncthreads();
  }
  // pool3: traced bit 2
  if (tid < 16) {
    int u = tid >> 2, v = tid & 3;
    float2 acc = {0.f, 0.f};
#pragma unroll
    for (int s = 0; s < 2; s++) {
      float2 x = r3[((s << 2) | u) * 8 + ((s << 2) | v)];
      acc.x += x.x; acc.y += x.y;
    }
    r4[u * 4 + v] = acc;
  }
  __syncthreads();

#pragma unroll
  for (int k = 0; k < 16; k++) { U[k] = Umat[64 + k]; Uc[k] = make_float2(U[k].x, -U[k].y); }
  // layer 4 (nq=2): single gate = full 4x4 on ket, conj on bra
  if (tid < 4) {
    int j = tid;
    float2 v0 = r4[0 * 4 + j], v1 = r4[1 * 4 + j], v2 = r4[2 * 4 + j], v3 = r4[3 * 4 + j];
    gate4(v0, v1, v2, v3, U);
    r4[0 * 4 + j] = v0; r4[1 * 4 + j] = v1; r4[2 * 4 + j] = v2; r4[3 * 4 + j] = v3;
  }
  __syncthreads();
  if (tid < 4) {
    int i = tid;
    float2 v0 = r4[i * 4 + 0], v1 = r4[i * 4 + 1], v2 = r4[i * 4 + 2], v3 = r4[i * 4 + 3];
    gate4(v0, v1, v2, v3, Uc);
    r4[i * 4 + 0] = v0; r4[i * 4 + 1] = v1; r4[i * 4 + 2] = v2; r4[i * 4 + 3] = v3;
  }
  __syncthreads();
  // pool4 + measure: rho5[0,0] = r4[0,0] + r4[2,2]; output its real part
  if (tid == 0) out[b] = r4[0].x + r4[10].x;
}

// ---------------------------------------------------------------------------
extern "C" void kernel_launch(void* const* d_in, const int* in_sizes, int n_in,
                              void* d_out, int out_size, void* d_ws, size_t ws_size,
                              hipStream_t stream) {
  const float* psi_re = (const float*)d_in[0];
  const float* psi_im = (const float*)d_in[1];
  const float* H_re = (const float*)d_in[2];
  const float* H_im = (const float*)d_in[3];
  float* out = (float*)d_out;

  char* ws = (char*)d_ws;
  float2* Umat = (float2*)ws;                                   // 5*16 float2
  float2* state = (float2*)(ws + 4096);                         // 4M float2 = 32 MB
  float* partial = (float*)(ws + 4096 + ((size_t)1 << 25));     // 512*2048 floats = 4 MB
  float* rho32 = (float*)(ws + 4096 + ((size_t)1 << 25) + ((size_t)1 << 22));  // 8192 floats

  const size_t LDS_BYTES = 8704 * sizeof(float2);  // 8192 + pad

  hipLaunchKernelGGL(expm_kernel, dim3(1), dim3(320), 0, stream, H_re, H_im, Umat);
  hipLaunchKernelGGL(l0_pass1, dim3(512), dim3(256), LDS_BYTES, stream,
                     psi_re, psi_im, Umat, state);
  hipLaunchKernelGGL(l0_pass2, dim3(512), dim3(256), LDS_BYTES, stream, Umat, state);
  hipLaunchKernelGGL(pool_l1, dim3(512), dim3(256), LDS_BYTES, stream,
                     Umat, state, (float2*)partial);
  hipLaunchKernelGGL(reduce_partials, dim3(32), dim3(256), 0, stream, partial, rho32);
  hipLaunchKernelGGL(finish, dim3(4), dim3(256), 0, stream, Umat, (const float2*)rho32, out);
}

// Round 3
// 204.952 us; speedup vs baseline: 1.5637x; 1.1670x over previous
//
#include <hip/hip_runtime.h>
#include <math.h>

// ---------------------------------------------------------------------------
// QCNN forward, restructured:
//   layer0 gates (20x two-qubit, 2 LDS passes, gate-paired 16-elem register
//   phases) -> per-row-vector layer1 gates + pooled outer products (avoids
//   the 1024^3 complex GEMM) -> tiny tail.
// Bit convention: qubit q <-> address bit (19-q)  (qubit 0 = MSB).
// Gate digit r = 2*bit(pa) + bit(pb).
// pool_l1 LDS layout: (t_lo, s, u) with row stride 33 (odd => bank-uniform).
// ---------------------------------------------------------------------------

__device__ __forceinline__ float2 cmul(float2 a, float2 b) {
  return make_float2(a.x * b.x - a.y * b.y, a.x * b.y + a.y * b.x);
}
__device__ __forceinline__ float2 cmadd(float2 acc, float2 a, float2 b) {
  acc.x = fmaf(a.x, b.x, fmaf(-a.y, b.y, acc.x));
  acc.y = fmaf(a.x, b.y, fmaf(a.y, b.x, acc.y));
  return acc;
}
// acc += a * conj(b)
__device__ __forceinline__ float2 cmaddc(float2 acc, float2 a, float2 b) {
  acc.x = fmaf(a.x, b.x, fmaf(a.y, b.y, acc.x));
  acc.y = fmaf(a.y, b.x, fmaf(-a.x, b.y, acc.y));
  return acc;
}
// LDS pad for l0 tiles: +1 float2 every 16 to break power-of-2 strides
__device__ __forceinline__ int pad(int e) { return e + (e >> 4); }

// spread bits: bit j -> bit 2j, valid for v < 2^16
__device__ __forceinline__ unsigned spread(unsigned v) {
  v = (v | (v << 8)) & 0x00FF00FFu;
  v = (v | (v << 4)) & 0x0F0F0F0Fu;
  v = (v | (v << 2)) & 0x33333333u;
  v = (v | (v << 1)) & 0x55555555u;
  return v;
}
// bit j -> bit 4j
__device__ __forceinline__ unsigned spread2(unsigned v) { return spread(spread(v)); }
// insert a zero bit at (final) position p
__device__ __forceinline__ int ins(int x, int p) {
  return ((x >> p) << (p + 1)) | (x & ((1 << p) - 1));
}

__device__ __forceinline__ void gate4(float2& v0, float2& v1, float2& v2, float2& v3,
                                      const float2 (&U)[16]) {
  float2 n0 = cmul(U[0], v0);  n0 = cmadd(n0, U[1], v1);  n0 = cmadd(n0, U[2], v2);  n0 = cmadd(n0, U[3], v3);
  float2 n1 = cmul(U[4], v0);  n1 = cmadd(n1, U[5], v1);  n1 = cmadd(n1, U[6], v2);  n1 = cmadd(n1, U[7], v3);
  float2 n2 = cmul(U[8], v0);  n2 = cmadd(n2, U[9], v1);  n2 = cmadd(n2, U[10], v2); n2 = cmadd(n2, U[11], v3);
  float2 n3 = cmul(U[12], v0); n3 = cmadd(n3, U[13], v1); n3 = cmadd(n3, U[14], v2); n3 = cmadd(n3, U[15], v3);
  v0 = n0; v1 = n1; v2 = n2; v3 = n3;
}

// two commuting gates on a 16-element register subspace:
// gate (local bits 1,0) then gate (local bits 3,2); v[j]: bit k of j <-> local bit k
__device__ __forceinline__ void gate16(float2 (&v)[16], const float2 (&U)[16]) {
#pragma unroll
  for (int g = 0; g < 4; g++)
    gate4(v[g * 4 + 0], v[g * 4 + 1], v[g * 4 + 2], v[g * 4 + 3], U);
#pragma unroll
  for (int lo = 0; lo < 4; lo++)
    gate4(v[lo], v[lo + 4], v[lo + 8], v[lo + 12], U);
}

// single 2-qubit gate at bit positions (pa, pb) over a padded 2^13 LDS tile
__device__ __forceinline__ void apply_gate_tile13(float2* t, const float2 (&U)[16],
                                                  int pa, int pb, int tid) {
  int p0 = pa < pb ? pa : pb;
  int p1 = pa < pb ? pb : pa;
  int m0 = (1 << p0) - 1, m1 = (1 << p1) - 1;
  int ia = 1 << pa, ib = 1 << pb;
#pragma unroll
  for (int g = tid; g < 2048; g += 256) {
    int idx = ((g & ~m0) << 1) | (g & m0);
    idx = ((idx & ~m1) << 1) | (idx & m1);
    int e0 = pad(idx), e1 = pad(idx | ib), e2 = pad(idx | ia), e3 = pad(idx | ia | ib);
    float2 v0 = t[e0], v1 = t[e1], v2 = t[e2], v3 = t[e3];
    gate4(v0, v1, v2, v3, U);
    t[e0] = v0; t[e1] = v1; t[e2] = v2; t[e3] = v3;
  }
}

// paired-gate phase over bits {p0<p1<p2<p3} of a padded 2^13 LDS tile:
// applies gates (p1,p0) and (p3,p2)
__device__ __forceinline__ void phase4_l0(float2* t, const float2 (&U)[16],
                                          int p0, int p1, int p2, int p3, int tid) {
  int o0 = 1 << p0, o1 = 1 << p1, o2 = 1 << p2, o3 = 1 << p3;
#pragma unroll
  for (int it = 0; it < 2; it++) {
    int h = tid + it * 256;
    int idx = ins(ins(ins(ins(h, p0), p1), p2), p3);
    float2 v[16];
#pragma unroll
    for (int j = 0; j < 16; j++) {
      int off = ((j & 1) ? o0 : 0) + ((j & 2) ? o1 : 0) + ((j & 4) ? o2 : 0) + ((j & 8) ? o3 : 0);
      v[j] = t[pad(idx + off)];
    }
    gate16(v, U);
#pragma unroll
    for (int j = 0; j < 16; j++) {
      int off = ((j & 1) ? o0 : 0) + ((j & 2) ? o1 : 0) + ((j & 4) ? o2 : 0) + ((j & 8) ? o3 : 0);
      t[pad(idx + off)] = v[j];
    }
  }
}

// pool LDS (t_lo,s,u) stride-33 helpers ---------------------------------------
// paired-gate phase: removes u-bits {a_lo<a_hi} and s-bits {c_lo<c_hi};
// offsets o0..o3 are the flat strides of local bits 0..3;
// applies gates (local 1,0) then (local 3,2)
__device__ __forceinline__ void phase4_pool(float2* w, const float2 (&U)[16],
                                            int a_lo, int a_hi, int c_lo, int c_hi,
                                            int o0, int o1, int o2, int o3, int tid) {
#pragma unroll
  for (int it = 0; it < 2; it++) {
    int h = tid + it * 256;
    int uu = h & 7, ss = (h >> 3) & 7, t_lo = h >> 6;
    int u = ins(ins(uu, a_lo), a_hi);
    int s = ins(ins(ss, c_lo), c_hi);
    int base = t_lo * 1056 + s * 33 + u;
    float2 v[16];
#pragma unroll
    for (int j = 0; j < 16; j++) {
      int off = ((j & 1) ? o0 : 0) + ((j & 2) ? o1 : 0) + ((j & 4) ? o2 : 0) + ((j & 8) ? o3 : 0);
      v[j] = w[base + off];
    }
    gate16(v, U);
#pragma unroll
    for (int j = 0; j < 16; j++) {
      int off = ((j & 1) ? o0 : 0) + ((j & 2) ? o1 : 0) + ((j & 4) ? o2 : 0) + ((j & 8) ? o3 : 0);
      w[base + off] = v[j];
    }
  }
}

// single gate: removes u-bit a and s-bit c; pa-offset offa, pb-offset offb
__device__ __forceinline__ void gate_su(float2* w, const float2 (&U)[16],
                                        int a, int c, int offa, int offb, int tid) {
#pragma unroll
  for (int g = tid; g < 2048; g += 256) {
    int uu = g & 15, ss = (g >> 4) & 15, t_lo = g >> 8;
    int u = ins(uu, a), s = ins(ss, c);
    int base = t_lo * 1056 + s * 33 + u;
    float2 v0 = w[base], v1 = w[base + offb], v2 = w[base + offa], v3 = w[base + offa + offb];
    gate4(v0, v1, v2, v3, U);
    w[base] = v0; w[base + offb] = v1; w[base + offa] = v2; w[base + offa + offb] = v3;
  }
}

// ---------------------------------------------------------------------------
// Kernel A: U[l] = expm(A - A^H), fp64, lane-parallel (16 lanes per matrix)
// ---------------------------------------------------------------------------
__global__ __launch_bounds__(320) void expm_kernel(const float* __restrict__ Hre,
                                                   const float* __restrict__ Him,
                                                   float2* __restrict__ Uout) {
  int wave = threadIdx.x >> 6;
  int lane = threadIdx.x & 63;
  if (wave >= 5 || lane >= 16) return;
  int l = wave;
  int r = lane >> 2, c = lane & 3;
  double tr = (double)Hre[l * 16 + r * 4 + c] - (double)Hre[l * 16 + c * 4 + r];
  double ti = (double)Him[l * 16 + r * 4 + c] + (double)Him[l * 16 + c * 4 + r];
  double a = sqrt(tr * tr + ti * ti);
  a += __shfl_xor(a, 1, 64);
  a += __shfl_xor(a, 2, 64);
  double nrm = fmax(a, __shfl_xor(a, 4, 64));
  nrm = fmax(nrm, __shfl_xor(nrm, 8, 64));
  int s = 0;
  while (nrm > 0.25 && s < 60) { nrm *= 0.5; s++; }
  double sc = ldexp(1.0, -s);
  tr *= sc; ti *= sc;
  double id = (r == c) ? 1.0 : 0.0;
  double er = id, ei = 0.0, pr = id, pi = 0.0;
  for (int k = 1; k <= 16; k++) {
    double qr = 0.0, qi = 0.0;
#pragma unroll
    for (int m = 0; m < 4; m++) {
      double pmr = __shfl(pr, r * 4 + m, 64);
      double pmi = __shfl(pi, r * 4 + m, 64);
      double tmr = __shfl(tr, m * 4 + c, 64);
      double tmi = __shfl(ti, m * 4 + c, 64);
      qr = fma(pmr, tmr, fma(-pmi, tmi, qr));
      qi = fma(pmr, tmi, fma(pmi, tmr, qi));
    }
    double inv = 1.0 / (double)k;
    pr = qr * inv; pi = qi * inv;
    er += pr; ei += pi;
  }
  for (int it = 0; it < s; it++) {
    double qr = 0.0, qi = 0.0;
#pragma unroll
    for (int m = 0; m < 4; m++) {
      double amr = __shfl(er, r * 4 + m, 64);
      double ami = __shfl(ei, r * 4 + m, 64);
      double bmr = __shfl(er, m * 4 + c, 64);
      double bmi = __shfl(ei, m * 4 + c, 64);
      qr = fma(amr, bmr, fma(-ami, bmi, qr));
      qi = fma(amr, bmi, fma(ami, bmr, qi));
    }
    er = qr; ei = qi;
  }
  Uout[l * 16 + lane] = make_float2((float)er, (float)ei);
}

// ---------------------------------------------------------------------------
// Kernel B: layer-0 pass 1. Tile = addr bits 0..12.
// Evens {1,0}..{11,10} then odds {2,1}..{10,9}, gate-paired.
// ---------------------------------------------------------------------------
__global__ __launch_bounds__(256) void l0_pass1(const float* __restrict__ pre,
                                                const float* __restrict__ pim,
                                                const float2* __restrict__ Umat,
                                                float2* __restrict__ state) {
  extern __shared__ float2 tile[];
  int tid = threadIdx.x;
  int bid = blockIdx.x;
  int b = bid >> 7, hi = bid & 127;
  size_t base = ((size_t)b << 20) | ((size_t)hi << 13);
  float2 U[16];
#pragma unroll
  for (int k = 0; k < 16; k++) U[k] = Umat[k];
  for (int e = tid; e < 8192; e += 256)
    tile[pad(e)] = make_float2(pre[base + e], pim[base + e]);
  __syncthreads();
  phase4_l0(tile, U, 0, 1, 2, 3, tid);   __syncthreads();  // {1,0},{3,2}
  phase4_l0(tile, U, 4, 5, 6, 7, tid);   __syncthreads();  // {5,4},{7,6}
  phase4_l0(tile, U, 8, 9, 10, 11, tid); __syncthreads();  // {9,8},{11,10}
  phase4_l0(tile, U, 1, 2, 3, 4, tid);   __syncthreads();  // {2,1},{4,3}
  phase4_l0(tile, U, 5, 6, 7, 8, tid);   __syncthreads();  // {6,5},{8,7}
  apply_gate_tile13(tile, U, 10, 9, tid); __syncthreads(); // {10,9}
  for (int e = tid; e < 8192; e += 256) state[base + e] = tile[pad(e)];
}

// ---------------------------------------------------------------------------
// Kernel C: layer-0 pass 2. Tile = addr bits {0..3} U {11..19} (local 0..12).
// Evens {6,5},{8,7},{10,9},{12,11}; odds {5,4}..{11,10}; wrap {0,12}.
// ---------------------------------------------------------------------------
__global__ __launch_bounds__(256) void l0_pass2(const float2* __restrict__ Umat,
                                                float2* __restrict__ state) {
  extern __shared__ float2 tile[];
  int tid = threadIdx.x;
  int bid = blockIdx.x;
  int b = bid >> 7, mid = bid & 127;
  size_t base = ((size_t)b << 20) | ((size_t)mid << 4);
  float2 U[16];
#pragma unroll
  for (int k = 0; k < 16; k++) U[k] = Umat[k];
  for (int e = tid; e < 8192; e += 256) {
    size_t a = base + (((size_t)(e >> 4)) << 11) + (size_t)(e & 15);
    tile[pad(e)] = state[a];
  }
  __syncthreads();
  phase4_l0(tile, U, 5, 6, 7, 8, tid);    __syncthreads(); // {6,5},{8,7}
  phase4_l0(tile, U, 9, 10, 11, 12, tid); __syncthreads(); // {10,9},{12,11}
  phase4_l0(tile, U, 4, 5, 6, 7, tid);    __syncthreads(); // {5,4},{7,6}
  phase4_l0(tile, U, 8, 9, 10, 11, tid);  __syncthreads(); // {9,8},{11,10}
  apply_gate_tile13(tile, U, 0, 12, tid); __syncthreads(); // wrap {0,12}
  for (int e = tid; e < 8192; e += 256) {
    size_t a = base + (((size_t)(e >> 4)) << 11) + (size_t)(e & 15);
    state[a] = tile[pad(e)];
  }
}

// ---------------------------------------------------------------------------
// Kernel D: pool0 + layer1 gates + pool1 partials.
// LDS layout w[t_lo*1056 + s*33 + u]; layer-1 gates strided; outer product
// 4x4-blocked, 1 wave = full 32x32 tile, rows split over 4 waves + LDS reduce.
// ---------------------------------------------------------------------------
__global__ __launch_bounds__(256) void pool_l1(const float2* __restrict__ Umat,
                                               const float2* __restrict__ state,
                                               float2* __restrict__ partial) {
  extern __shared__ float2 w[];  // 8448 float2
  int tid = threadIdx.x;
  int bid = blockIdx.x;
  int b = bid >> 7, thi = bid & 127;
  size_t bbase = (size_t)b << 20;
  float2 U[16];
#pragma unroll
  for (int k = 0; k < 16; k++) U[k] = Umat[16 + k];
  unsigned tbase = spread((unsigned)(thi << 3)) << 1;  // t-high bits at odd addr bits 7..19
  // gather: addr = u at bits 4j, s at bits 4j+2, t at odd bits
  for (int e = tid; e < 8192; e += 256) {
    int u = e & 31, s = (e >> 5) & 31, t_lo = e >> 10;
    unsigned addr = tbase | (spread((unsigned)t_lo) << 1) | spread2((unsigned)u)
                  | (spread2((unsigned)s) << 2);
    w[t_lo * 1056 + s * 33 + u] = state[bbase + (size_t)addr];
  }
  __syncthreads();
  // layer-1 gates (i-bit pairs; u-bit k stride 2^k, s-bit k stride 33*2^k)
  // evens: {9,8}+{7,6}, {5,4}+{3,2}, {1,0}; odds: {8,7}+{6,5}, {4,3}+{2,1}, {0,9}
  phase4_pool(w, U, 3, 4, 3, 4, 8, 264, 16, 528, tid);  __syncthreads(); // {7,6},{9,8}
  phase4_pool(w, U, 1, 2, 1, 2, 2, 66, 4, 132, tid);    __syncthreads(); // {3,2},{5,4}
  gate_su(w, U, 0, 0, 33, 1, tid);                      __syncthreads(); // {1,0}
  phase4_pool(w, U, 3, 4, 2, 3, 132, 8, 264, 16, tid);  __syncthreads(); // {6,5},{8,7}
  phase4_pool(w, U, 1, 2, 0, 1, 33, 2, 66, 4, tid);     __syncthreads(); // {2,1},{4,3}
  gate_su(w, U, 0, 4, 1, 528, tid);                     __syncthreads(); // {0,9}
  // pool1: rho2[u,v] = sum_{t_lo,s} w[t,s,u]*conj(w[t,s,v]); 4x4 per lane,
  // each wave covers the full 32x32, waves split t_lo
  int wv = tid >> 6, lane = tid & 63;
  int u0 = (lane >> 3) << 2, v0 = (lane & 7) << 2;
  float2 acc[4][4];
#pragma unroll
  for (int i = 0; i < 4; i++)
#pragma unroll
    for (int j = 0; j < 4; j++) acc[i][j] = make_float2(0.f, 0.f);
  for (int tl = 0; tl < 2; tl++) {
    int tb = (wv * 2 + tl) * 1056;
#pragma unroll 4
    for (int s = 0; s < 32; s++) {
      int row = tb + s * 33;
      float2 x[4], y[4];
#pragma unroll
      for (int i = 0; i < 4; i++) { x[i] = w[row + u0 + i]; y[i] = w[row + v0 + i]; }
#pragma unroll
      for (int i = 0; i < 4; i++)
#pragma unroll
        for (int j = 0; j < 4; j++) acc[i][j] = cmaddc(acc[i][j], x[i], y[j]);
    }
  }
  __syncthreads();  // w is dead; reuse for cross-wave reduction
  if (wv > 0) {
#pragma unroll
    for (int i = 0; i < 4; i++)
#pragma unroll
      for (int j = 0; j < 4; j++)
        w[(wv - 1) * 1024 + (u0 + i) * 32 + (v0 + j)] = acc[i][j];
  }
  __syncthreads();
  if (wv == 0) {
    float2* outp = partial + ((size_t)bid << 10);
#pragma unroll
    for (int i = 0; i < 4; i++)
#pragma unroll
      for (int j = 0; j < 4; j++) {
        float2 a = acc[i][j];
#pragma unroll
        for (int k = 0; k < 3; k++) {
          float2 o = w[k * 1024 + (u0 + i) * 32 + (v0 + j)];
          a.x += o.x; a.y += o.y;
        }
        outp[(u0 + i) * 32 + (v0 + j)] = a;
      }
  }
}

// ---------------------------------------------------------------------------
// Kernel E: reduce 128 partials per batch -> rho32
// ---------------------------------------------------------------------------
__global__ __launch_bounds__(256) void reduce_partials(const float* __restrict__ partial,
                                                       float* __restrict__ rho32) {
  int idx = blockIdx.x * 256 + threadIdx.x;  // 0..8191
  int b = idx >> 11, p = idx & 2047;
  float acc = 0.f;
#pragma unroll 4
  for (int h = 0; h < 128; h++) acc += partial[(((size_t)(b * 128 + h)) << 11) + (size_t)p];
  rho32[idx] = acc;
}

// ---------------------------------------------------------------------------
// Kernel F: layers 2..4 (32x32 -> 2x2 dm) + measure. One block per batch.
// ---------------------------------------------------------------------------
__global__ __launch_bounds__(256) void finish(const float2* __restrict__ Umat,
                                              const float2* __restrict__ rho32,
                                              float* __restrict__ out) {
  __shared__ float2 rho[1024];
  __shared__ float2 r3[64];
  __shared__ float2 r4[16];
  int tid = threadIdx.x;
  int b = blockIdx.x;
  for (int p = tid; p < 1024; p += 256) rho[p] = rho32[(b << 10) + p];
  __syncthreads();

  float2 U[16], Uc[16];
#pragma unroll
  for (int k = 0; k < 16; k++) { U[k] = Umat[32 + k]; Uc[k] = make_float2(U[k].x, -U[k].y); }
  const int gl2[4][2] = {{4,3},{2,1},{3,2},{1,0}};
#pragma unroll
  for (int gi = 0; gi < 4; gi++) {
    int pa = gl2[gi][0], pb = gl2[gi][1];
    int p0 = pa < pb ? pa : pb, p1 = pa < pb ? pb : pa;
    int m0 = (1 << p0) - 1, m1 = (1 << p1) - 1;
    int ia = 1 << pa, ib = 1 << pb;
    {
      int j = tid >> 3, g = tid & 7;
      int idx = ((g & ~m0) << 1) | (g & m0);
      idx = ((idx & ~m1) << 1) | (idx & m1);
      float2 v0 = rho[idx * 32 + j], v1 = rho[(idx | ib) * 32 + j];
      float2 v2 = rho[(idx | ia) * 32 + j], v3 = rho[(idx | ia | ib) * 32 + j];
      gate4(v0, v1, v2, v3, U);
      rho[idx * 32 + j] = v0; rho[(idx | ib) * 32 + j] = v1;
      rho[(idx | ia) * 32 + j] = v2; rho[(idx | ia | ib) * 32 + j] = v3;
    }
    __syncthreads();
    {
      int i = tid >> 3, g = tid & 7;
      int idx = ((g & ~m0) << 1) | (g & m0);
      idx = ((idx & ~m1) << 1) | (idx & m1);
      float2 v0 = rho[i * 32 + idx], v1 = rho[i * 32 + (idx | ib)];
      float2 v2 = rho[i * 32 + (idx | ia)], v3 = rho[i * 32 + (idx | ia | ib)];
      gate4(v0, v1, v2, v3, Uc);
      rho[i * 32 + idx] = v0; rho[i * 32 + (idx | ib)] = v1;
      rho[i * 32 + (idx | ia)] = v2; rho[i * 32 + (idx | ia | ib)] = v3;
    }
    __syncthreads();
  }
  if (tid < 64) {
    int u = tid >> 3, v = tid & 7;
    float2 acc = {0.f, 0.f};
#pragma unroll
    for (int s = 0; s < 4; s++) {
      int iu = ((s >> 1) << 4) | ((u >> 2) << 3) | ((s & 1) << 2) | (((u >> 1) & 1) << 1) | (u & 1);
      int iv = ((s >> 1) << 4) | ((v >> 2) << 3) | ((s & 1) << 2) | (((v >> 1) & 1) << 1) | (v & 1);
      float2 x = rho[iu * 32 + iv];
      acc.x += x.x; acc.y += x.y;
    }
    r3[u * 8 + v] = acc;
  }
  __syncthreads();

#pragma unroll
  for (int k = 0; k < 16; k++) { U[k] = Umat[48 + k]; Uc[k] = make_float2(U[k].x, -U[k].y); }
  const int gl3[2][2] = {{2,1},{1,0}};
#pragma unroll
  for (int gi = 0; gi < 2; gi++) {
    int pa = gl3[gi][0], pb = gl3[gi][1];
    int p0 = pa < pb ? pa : pb, p1 = pa < pb ? pb : pa;
    int m0 = (1 << p0) - 1, m1 = (1 << p1) - 1;
    int ia = 1 << pa, ib = 1 << pb;
    if (tid < 16) {
      int j = tid >> 1, g = tid & 1;
      int idx = ((g & ~m0) << 1) | (g & m0);
      idx = ((idx & ~m1) << 1) | (idx & m1);
      float2 v0 = r3[idx * 8 + j], v1 = r3[(idx | ib) * 8 + j];
      float2 v2 = r3[(idx | ia) * 8 + j], v3 = r3[(idx | ia | ib) * 8 + j];
      gate4(v0, v1, v2, v3, U);
      r3[idx * 8 + j] = v0; r3[(idx | ib) * 8 + j] = v1;
      r3[(idx | ia) * 8 + j] = v2; r3[(idx | ia | ib) * 8 + j] = v3;
    }
    __syncthreads();
    if (tid < 16) {
      int i = tid >> 1, g = tid & 1;
      int idx = ((g & ~m0) << 1) | (g & m0);
      idx = ((idx & ~m1) << 1) | (idx & m1);
      float2 v0 = r3[i * 8 + idx], v1 = r3[i * 8 + (idx | ib)];
      float2 v2 = r3[i * 8 + (idx | ia)], v3 = r3[i * 8 + (idx | ia | ib)];
      gate4(v0, v1, v2, v3, Uc);
      r3[i * 8 + idx] = v0; r3[i * 8 + (idx | ib)] = v1;
      r3[i * 8 + (idx | ia)] = v2; r3[i * 8 + (idx | ia | ib)] = v3;
    }
    __syncthreads();
  }
  if (tid < 16) {
    int u = tid >> 2, v = tid & 3;
    float2 acc = {0.f, 0.f};
#pragma unroll
    for (int s = 0; s < 2; s++) {
      float2 x = r3[((s << 2) | u) * 8 + ((s << 2) | v)];
      acc.x += x.x; acc.y += x.y;
    }
    r4[u * 4 + v] = acc;
  }
  __syncthreads();

#pragma unroll
  for (int k = 0; k < 16; k++) { U[k] = Umat[64 + k]; Uc[k] = make_float2(U[k].x, -U[k].y); }
  if (tid < 4) {
    int j = tid;
    float2 v0 = r4[0 * 4 + j], v1 = r4[1 * 4 + j], v2 = r4[2 * 4 + j], v3 = r4[3 * 4 + j];
    gate4(v0, v1, v2, v3, U);
    r4[0 * 4 + j] = v0; r4[1 * 4 + j] = v1; r4[2 * 4 + j] = v2; r4[3 * 4 + j] = v3;
  }
  __syncthreads();
  if (tid < 4) {
    int i = tid;
    float2 v0 = r4[i * 4 + 0], v1 = r4[i * 4 + 1], v2 = r4[i * 4 + 2], v3 = r4[i * 4 + 3];
    gate4(v0, v1, v2, v3, Uc);
    r4[i * 4 + 0] = v0; r4[i * 4 + 1] = v1; r4[i * 4 + 2] = v2; r4[i * 4 + 3] = v3;
  }
  __syncthreads();
  if (tid == 0) out[b] = r4[0].x + r4[10].x;
}

// ---------------------------------------------------------------------------
extern "C" void kernel_launch(void* const* d_in, const int* in_sizes, int n_in,
                              void* d_out, int out_size, void* d_ws, size_t ws_size,
                              hipStream_t stream) {
  const float* psi_re = (const float*)d_in[0];
  const float* psi_im = (const float*)d_in[1];
  const float* H_re = (const float*)d_in[2];
  const float* H_im = (const float*)d_in[3];
  float* out = (float*)d_out;

  char* ws = (char*)d_ws;
  float2* Umat = (float2*)ws;                                   // 5*16 float2
  float2* state = (float2*)(ws + 4096);                         // 4M float2 = 32 MB
  float* partial = (float*)(ws + 4096 + ((size_t)1 << 25));     // 512*2048 floats = 4 MB
  float* rho32 = (float*)(ws + 4096 + ((size_t)1 << 25) + ((size_t)1 << 22));  // 8192 floats

  const size_t LDS_L0 = 8704 * sizeof(float2);    // padded 8192
  const size_t LDS_POOL = 8448 * sizeof(float2);  // 8*1056 stride-33 rows

  hipLaunchKernelGGL(expm_kernel, dim3(1), dim3(320), 0, stream, H_re, H_im, Umat);
  hipLaunchKernelGGL(l0_pass1, dim3(512), dim3(256), LDS_L0, stream,
                     psi_re, psi_im, Umat, state);
  hipLaunchKernelGGL(l0_pass2, dim3(512), dim3(256), LDS_L0, stream, Umat, state);
  hipLaunchKernelGGL(pool_l1, dim3(512), dim3(256), LDS_POOL, stream,
                     Umat, state, (float2*)partial);
  hipLaunchKernelGGL(reduce_partials, dim3(32), dim3(256), 0, stream, partial, rho32);
  hipLaunchKernelGGL(finish, dim3(4), dim3(256), 0, stream, Umat, (const float2*)rho32, out);
}